// Round 8
// baseline (323.590 us; speedup 1.0000x reference)
//
#include <hip/hip_runtime.h>
#include <math.h>

// Problem dims (fixed)
constexpr int NB  = 8;    // batch
constexpr int NR  = 128;  // rule nodes
constexpr int HID = 256;  // hidden
constexpr int NIN = 512;  // input dim
constexpr int DHD = 64;   // head dim
constexpr size_t SZ = (size_t)NB * NR * HID;  // 262144

struct KP {
    const float *x, *We, *be, *msg_W1, *msg_b1, *msg_W2, *msg_b2;
    const float *upd_W1, *upd_b1, *upd_W2, *upd_b2, *ln_g, *ln_b, *rule_adj;
    const float *Wq, *bq, *Wk, *bk, *Wv, *bv, *Wo, *bo, *ro_W1, *ro_b1, *ro_W2, *ro_b2;
    float* out;
    float *N0, *N1;                      // normalized h streams
    float *aB, *bbB, *p1B;               // proj set B (layer inputs / qkv)
    float *aA, *bbA, *p1A;               // proj set A
    float *W2u, *mb2u, *Aw, *rsum;       // W2u[l] = msg_W2[l]@upd_W1b[l]
    float *mW1s;                         // layer0: msg_W1a + msg_W1b
    float *h0g;
    float *c0g, *c1g;                    // per-batch layer0 head-chain results
    float *gacc;                         // tail mean accumulator [8,256]
    float *scratch;
    unsigned* bars;                      // [0] = global barrier counter
};

// ---------------------------------------------------------------------------
// Shared-memory stage unions (one block = one CU, 1 block resident).
// ---------------------------------------------------------------------------
struct MainS {
    float u1s[4][HID];
    float nrm[4][HID];
    float ap[4][HID];
    float h0s[HID];
    float awr[4][NR];
    float sred[4][4][2];
    float part3[3][4][4][HID];   // 48 KB
};
struct AttnS {
    float KhT[64][128];          // 32 KB
    float S[16][128];
    float qs[16][64];
    float red[16][64];
};
struct SetupS {
    float rows[4][HID];
    float part[4][4][HID];
    float xs[NIN];
};
struct TailS {
    float v0[HID], v1[HID], v2[HID];
    float part[4][HID];          // reused as [8][128]
    float led[NR], el[NR];
};
union ShU { MainS m; AttnS a; SetupS s; TailS tl; };

// ---------------------------------------------------------------------------
// Global device barrier (monotonic ticket). Release/acquire via __threadfence
// (device scope -> cross-XCD safe). All 256 blocks resident (1 block/CU).
// ALL blocks run the same stage between barriers -> weight sets stay L2-shared
// (round-7's per-batch drift caused 51.7 MB FETCH / L2 thrash).
// ---------------------------------------------------------------------------
__device__ __forceinline__ void sync_bar(unsigned* bar, unsigned members) {
    __syncthreads();
    if (threadIdx.x == 0) {
        __threadfence();                           // release prior writes
        unsigned ticket = atomicAdd(bar, 1u);
        unsigned target = (ticket / members + 1u) * members;
        while (atomicAdd(bar, 0u) < target) __builtin_amdgcn_s_sleep(8);
        __threadfence();                           // acquire (invalidate)
    }
    __syncthreads();
}

// ---------------------------------------------------------------------------
// k-quarter partial of rows4 matmul: col in [0,256), q in [0,4).
// ---------------------------------------------------------------------------
__device__ __forceinline__ void rows4_q(
    const float (&rows)[4][HID], const float* __restrict__ W,
    int col, int q, float o[4])
{
    o[0] = o[1] = o[2] = o[3] = 0.f;
    int kb = q * 64;
#pragma unroll 4
    for (int k0 = 0; k0 < 64; k0 += 4) {
        int k = kb + k0;
        float w0 = W[(size_t)(k + 0) * HID + col];
        float w1 = W[(size_t)(k + 1) * HID + col];
        float w2 = W[(size_t)(k + 2) * HID + col];
        float w3 = W[(size_t)(k + 3) * HID + col];
#pragma unroll
        for (int ii = 0; ii < 4; ++ii) {
            float4 rv = *(const float4*)&rows[ii][k];
            o[ii] += rv.x * w0 + rv.y * w1 + rv.z * w2 + rv.w * w3;
        }
    }
}

// Same partial for THREE weight matrices in one pass.
__device__ __forceinline__ void rows4_q3(
    const float (&rows)[4][HID],
    const float* __restrict__ W0, const float* __restrict__ W1,
    const float* __restrict__ W2m,
    int col, int q, float o[3][4])
{
#pragma unroll
    for (int p = 0; p < 3; ++p)
#pragma unroll
        for (int ii = 0; ii < 4; ++ii) o[p][ii] = 0.f;
    int kb = q * 64;
#pragma unroll 2
    for (int k0 = 0; k0 < 64; k0 += 4) {
        int k = kb + k0;
        float4 rv[4];
#pragma unroll
        for (int ii = 0; ii < 4; ++ii) rv[ii] = *(const float4*)&rows[ii][k];
        const float* Wp[3] = {W0, W1, W2m};
#pragma unroll
        for (int p = 0; p < 3; ++p) {
            const float* W = Wp[p];
            float w0 = W[(size_t)(k + 0) * HID + col];
            float w1 = W[(size_t)(k + 1) * HID + col];
            float w2 = W[(size_t)(k + 2) * HID + col];
            float w3 = W[(size_t)(k + 3) * HID + col];
#pragma unroll
            for (int ii = 0; ii < 4; ++ii)
                o[p][ii] += rv[ii].x * w0 + rv[ii].y * w1
                          + rv[ii].z * w2 + rv[ii].w * w3;
        }
    }
}

// Single-row k-quarter GEMV partial.
__device__ __forceinline__ float gemv_q(
    const float* xs, const float* __restrict__ W, int col, int q)
{
    float o = 0.f;
    int kb = q * 64;
#pragma unroll 8
    for (int k = 0; k < 64; ++k)
        o += xs[kb + k] * W[(size_t)(kb + k) * HID + col];
    return o;
}

// ---------------------------------------------------------------------------
// Stage: fused aggregate + u1 + resid + LN + fused next-layer projection.
// ---------------------------------------------------------------------------
__device__ void aggproj_stage(ShU& sh, const KP& P, int b, int i0, int m0, int t,
    const float* __restrict__ a, const float* __restrict__ bbv,
    const float* __restrict__ mb1,
    const float* __restrict__ P1, const float* __restrict__ W2u,
    const float* __restrict__ mb2u, const float* __restrict__ ub1,
    const float* __restrict__ uW2, const float* __restrict__ ub2,
    const float* __restrict__ Nprev, const float* __restrict__ lng,
    const float* __restrict__ lnb, float* __restrict__ Nout,
    const float* __restrict__ pw0, const float* __restrict__ pb0, float* __restrict__ o0,
    const float* __restrict__ pw1, const float* __restrict__ pb1, float* __restrict__ o1,
    const float* __restrict__ pw2, const float* __restrict__ pb2, float* __restrict__ o2)
{
    int col = t & 255, q = t >> 8;
    int w4 = (t >> 6) & 3, l = t & 63;

    if (t < 512) sh.m.awr[t >> 7][t & 127] = P.Aw[(i0 + (t >> 7)) * NR + (t & 127)];

    float bias = mb1[col];
    float ai[4];
#pragma unroll
    for (int ii = 0; ii < 4; ++ii)
        ai[ii] = a[(size_t)(m0 + ii) * HID + col] + bias;
    __syncthreads();                                       // (1)

    {   // aggregate, j-quarter
        float acc[4] = {0.f, 0.f, 0.f, 0.f};
        const float* bbb = &bbv[(size_t)b * NR * HID + col];
        int jb = q * 32;
#pragma unroll 4
        for (int j = 0; j < 32; ++j) {
            float bj = bbb[(size_t)(jb + j) * HID];
#pragma unroll
            for (int ii = 0; ii < 4; ++ii) {
                float pre = fmaxf(ai[ii] + bj, 0.0f);
                acc[ii] += sh.m.awr[ii][jb + j] * pre;
            }
        }
#pragma unroll
        for (int ii = 0; ii < 4; ++ii) sh.m.part3[0][q][ii][col] = acc[ii];
    }
    __syncthreads();                                       // (2)
    sh.m.ap[q][col] = sh.m.part3[0][0][q][col] + sh.m.part3[0][1][q][col]
                    + sh.m.part3[0][2][q][col] + sh.m.part3[0][3][q][col];
    __syncthreads();                                       // (3)

    {   // W2u pass -> u1
        float o[4];
        rows4_q(sh.m.ap, W2u, col, q, o);
#pragma unroll
        for (int ii = 0; ii < 4; ++ii) sh.m.part3[0][q][ii][col] = o[ii];
    }
    __syncthreads();                                       // (4)
    {
        float w2f = sh.m.part3[0][0][q][col] + sh.m.part3[0][1][q][col]
                  + sh.m.part3[0][2][q][col] + sh.m.part3[0][3][q][col];
        float vv = w2f + P1[(size_t)(m0 + q) * HID + col]
                 + P.rsum[i0 + q] * mb2u[col] + ub1[col];
        sh.m.u1s[q][col] = fmaxf(vv, 0.0f);
    }
    __syncthreads();                                       // (5)

    {   // uW2 -> v, LN
        float o[4];
        rows4_q(sh.m.u1s, uW2, col, q, o);
#pragma unroll
        for (int ii = 0; ii < 4; ++ii) sh.m.part3[0][q][ii][col] = o[ii];
    }
    __syncthreads();                                       // (6)
    float v;
    {
        float uf = sh.m.part3[0][0][q][col] + sh.m.part3[0][1][q][col]
                 + sh.m.part3[0][2][q][col] + sh.m.part3[0][3][q][col];
        v = Nprev[(size_t)(m0 + q) * HID + col] + uf + ub2[col];
        float s = v, qq2 = v * v;
#pragma unroll
        for (int off = 32; off; off >>= 1) {
            s += __shfl_xor(s, off); qq2 += __shfl_xor(qq2, off);
        }
        if (l == 0) { sh.m.sred[q][w4][0] = s; sh.m.sred[q][w4][1] = qq2; }
    }
    __syncthreads();                                       // (7)
    {
        float ss  = sh.m.sred[q][0][0] + sh.m.sred[q][1][0]
                  + sh.m.sred[q][2][0] + sh.m.sred[q][3][0];
        float qq2 = sh.m.sred[q][0][1] + sh.m.sred[q][1][1]
                  + sh.m.sred[q][2][1] + sh.m.sred[q][3][1];
        float mu = ss * (1.0f / HID);
        float inv = rsqrtf(qq2 * (1.0f / HID) - mu * mu + 1e-5f);
        float nv = (v - mu) * inv * lng[col] + lnb[col];
        sh.m.nrm[q][col] = nv;
        if (Nout) Nout[(size_t)(m0 + q) * HID + col] = nv;
    }
    __syncthreads();                                       // (8)

    {   // fused 3 projections
        float o3[3][4];
        rows4_q3(sh.m.nrm, pw0, pw1, pw2, col, q, o3);
#pragma unroll
        for (int p = 0; p < 3; ++p)
#pragma unroll
            for (int ii = 0; ii < 4; ++ii) sh.m.part3[p][q][ii][col] = o3[p][ii];
    }
    __syncthreads();                                       // (9)
    if (q < 3) {
        const float* pb = (q == 0) ? pb0 : (q == 1) ? pb1 : pb2;
        float* po = (q == 0) ? o0 : (q == 1) ? o1 : o2;
        float pbv = pb ? pb[col] : 0.f;
#pragma unroll
        for (int ii = 0; ii < 4; ++ii) {
            float s = sh.m.part3[q][0][ii][col] + sh.m.part3[q][1][ii][col]
                    + sh.m.part3[q][2][ii][col] + sh.m.part3[q][3][ii][col] + pbv;
            po[(size_t)(m0 + ii) * HID + col] = s;
        }
    }
}

// ---------------------------------------------------------------------------
// Stage: layer 0 (head chain hoisted) + fused projection.
// ---------------------------------------------------------------------------
__device__ void layer0_stage(ShU& sh, const KP& P, int b, int i0, int m0, int t)
{
    int col = t & 255, q = t >> 8;
    int w4 = (t >> 6) & 3, l = t & 63;

    {
        float c0 = P.c0g[b * HID + col];
        float c1 = P.c1g[b * HID + col];
        if (q == 0) sh.m.h0s[col] = P.h0g[b * HID + col];
        sh.m.u1s[q][col] = fmaxf(c0 + P.rsum[i0 + q] * c1 + P.upd_b1[col], 0.0f);
    }
    __syncthreads();                                       // (1)

    {
        float o[4];
        rows4_q(sh.m.u1s, P.upd_W2, col, q, o);
#pragma unroll
        for (int ii = 0; ii < 4; ++ii) sh.m.part3[0][q][ii][col] = o[ii];
    }
    __syncthreads();                                       // (2)

    float v;
    {
        float h0v = sh.m.h0s[col] + P.upd_b2[col];
        v = sh.m.part3[0][0][q][col] + sh.m.part3[0][1][q][col]
          + sh.m.part3[0][2][q][col] + sh.m.part3[0][3][q][col] + h0v;
        float s = v, qq2 = v * v;
#pragma unroll
        for (int off = 32; off; off >>= 1) {
            s += __shfl_xor(s, off); qq2 += __shfl_xor(qq2, off);
        }
        if (l == 0) { sh.m.sred[q][w4][0] = s; sh.m.sred[q][w4][1] = qq2; }
    }
    __syncthreads();                                       // (3)
    {
        float ss  = sh.m.sred[q][0][0] + sh.m.sred[q][1][0]
                  + sh.m.sred[q][2][0] + sh.m.sred[q][3][0];
        float qq2 = sh.m.sred[q][0][1] + sh.m.sred[q][1][1]
                  + sh.m.sred[q][2][1] + sh.m.sred[q][3][1];
        float mu = ss * (1.0f / HID);
        float inv = rsqrtf(qq2 * (1.0f / HID) - mu * mu + 1e-5f);
        float nv = (v - mu) * inv * P.ln_g[col] + P.ln_b[col];
        sh.m.nrm[q][col] = nv;
        P.N0[(size_t)(m0 + q) * HID + col] = nv;
    }
    __syncthreads();                                       // (4)

    {
        const float* mW1a1 = P.msg_W1 + (size_t)1 * 2 * HID * HID;
        const float* uW1a1 = P.upd_W1 + (size_t)1 * 2 * HID * HID;
        float o3[3][4];
        rows4_q3(sh.m.nrm, mW1a1, mW1a1 + (size_t)HID * HID, uW1a1, col, q, o3);
#pragma unroll
        for (int p = 0; p < 3; ++p)
#pragma unroll
            for (int ii = 0; ii < 4; ++ii) sh.m.part3[p][q][ii][col] = o3[p][ii];
    }
    __syncthreads();                                       // (5)
    if (q < 3) {
        float* po = (q == 0) ? P.aB : (q == 1) ? P.bbB : P.p1B;
#pragma unroll
        for (int ii = 0; ii < 4; ++ii) {
            float s = sh.m.part3[q][0][ii][col] + sh.m.part3[q][1][ii][col]
                    + sh.m.part3[q][2][ii][col] + sh.m.part3[q][3][ii][col];
            po[(size_t)(m0 + ii) * HID + col] = s;
        }
    }
}

// ---------------------------------------------------------------------------
// Stage: attention unit (one (b, head, 16-row group) per block).
// K^T staging conflict-free: bank = j%32, 2 lanes/bank (free on CDNA4).
// ---------------------------------------------------------------------------
__device__ void attn_stage(AttnS& A, const KP& P, int b, int sl, int t)
{
    int hd = sl >> 3, ig = sl & 7, i0q = ig * 16;
    const float* qg = P.aB  + ((size_t)b * NR) * HID + hd * DHD;
    const float* kg = P.bbB + ((size_t)b * NR) * HID + hd * DHD;
    const float* vg = P.p1B + ((size_t)b * NR) * HID + hd * DHD;

    {   // stage K^T: j = t&127 (row), dseg = t>>7 (8-d slice)
        int j = t & 127, dseg = t >> 7;
        const float* kr = kg + (size_t)j * HID + dseg * 8;
        float4 a4 = *(const float4*)kr;
        float4 b4 = *(const float4*)(kr + 4);
        A.KhT[dseg * 8 + 0][j] = a4.x; A.KhT[dseg * 8 + 1][j] = a4.y;
        A.KhT[dseg * 8 + 2][j] = a4.z; A.KhT[dseg * 8 + 3][j] = a4.w;
        A.KhT[dseg * 8 + 4][j] = b4.x; A.KhT[dseg * 8 + 5][j] = b4.y;
        A.KhT[dseg * 8 + 6][j] = b4.z; A.KhT[dseg * 8 + 7][j] = b4.w;
    }
    {   // stage q rows
        int ii = t >> 6, d = t & 63;
        A.qs[ii][d] = qg[(size_t)(i0q + ii) * HID + d];
    }
    __syncthreads();
    {   // scores: rows {2*ii2, 2*ii2+1}
        int j = t & 127, ii2 = t >> 7;
        float a0 = 0.f, a1 = 0.f;
#pragma unroll 4
        for (int d = 0; d < 64; ++d) {
            float kv = A.KhT[d][j];
            a0 += A.qs[2 * ii2][d] * kv;
            a1 += A.qs[2 * ii2 + 1][d] * kv;
        }
        A.S[2 * ii2][j] = a0 * 0.125f;
        A.S[2 * ii2 + 1][j] = a1 * 0.125f;
    }
    __syncthreads();
    {   // softmax: wave w -> row w
        int w = t >> 6, l = t & 63;
        float e0 = A.S[w][l], e1 = A.S[w][l + 64];
        float mx = fmaxf(e0, e1);
#pragma unroll
        for (int off = 32; off; off >>= 1) mx = fmaxf(mx, __shfl_xor(mx, off));
        e0 = expf(e0 - mx); e1 = expf(e1 - mx);
        float sm = e0 + e1;
#pragma unroll
        for (int off = 32; off; off >>= 1) sm += __shfl_xor(sm, off);
        float inv = 1.0f / sm;
        A.S[w][l] = e0 * inv; A.S[w][l + 64] = e1 * inv;
    }
    __syncthreads();
    {   // PV: wave r -> row r, lane d
        int r = t >> 6, d = t & 63;
        float acc = 0.f;
        const float* vp = vg + d;
#pragma unroll 8
        for (int j = 0; j < NR; ++j) acc += A.S[r][j] * vp[(size_t)j * HID];
        A.red[r][d] = acc;
    }
    __syncthreads();
    if (t < 64) {
        float s = 0.f;
#pragma unroll
        for (int r = 0; r < 16; ++r) s += A.red[r][t];
        atomicAdd(&P.gacc[b * HID + hd * DHD + t], s);
    }
}

// ---------------------------------------------------------------------------
// Stage: tail (one block per batch).
// ---------------------------------------------------------------------------
__device__ void tail_stage(TailS& T, const KP& P, int b, int t)
{
    int col = t & 255, q = t >> 8;
    if (t < 256) T.v0[t] = P.gacc[b * HID + t] * (1.0f / NR);
    __syncthreads();
    T.part[q][col] = gemv_q(T.v0, P.Wo, col, q);
    __syncthreads();
    if (q == 0)
        T.v1[col] = T.part[0][col] + T.part[1][col] + T.part[2][col]
                  + T.part[3][col] + P.bo[col];
    __syncthreads();
    T.part[q][col] = gemv_q(T.v1, P.ro_W1, col, q);
    __syncthreads();
    if (q == 0)
        T.v2[col] = fmaxf(T.part[0][col] + T.part[1][col] + T.part[2][col]
                        + T.part[3][col] + P.ro_b1[col], 0.0f);
    __syncthreads();
    {   // logits: j in [0,128), 8-way k-split
        int j = t & 127, q8 = t >> 7;
        int kb = q8 * 32;
        float acc = 0.f;
#pragma unroll 8
        for (int k2 = 0; k2 < 32; ++k2)
            acc += T.v2[kb + k2] * P.ro_W2[(size_t)(kb + k2) * NR + j];
        float* pp = &T.part[0][0];
        pp[q8 * 128 + j] = acc;
    }
    __syncthreads();
    if (t < NR) {
        float* pp = &T.part[0][0];
        float s = 0.f;
#pragma unroll
        for (int p8 = 0; p8 < 8; ++p8) s += pp[p8 * 128 + t];
        T.led[t] = s + P.ro_b2[t];
    }
    __syncthreads();
    if (t < NR) {
        float m = -1e30f;
        for (int j = 0; j < NR; ++j) m = fmaxf(m, T.led[j]);
        T.el[t] = expf(T.led[t] - m);
    }
    __syncthreads();
    if (t < NR) {
        float tot = 0.f;
        for (int j = 0; j < NR; ++j) tot += T.el[j];
        P.out[b * NR + t] = T.el[t] / tot;
    }
}

// ---------------------------------------------------------------------------
// Persistent mega kernel: grid 256 x 1024. blk = b*32 + sl.
// GLOBAL barrier between every stage: all CUs run the same stage -> the
// stage's weight set is shared in L2 (fixes round-7's 51.7 MB FETCH thrash).
// ---------------------------------------------------------------------------
__global__ __launch_bounds__(1024) void mega_kernel(KP P)
{
    __shared__ ShU sh;
    int blk = blockIdx.x, t = threadIdx.x;
    int b = blk >> 5, sl = blk & 31;
    int i0 = sl * 4, m0 = b * NR + i0;
    unsigned* gbar = P.bars;

    // ================= S0: setup roles =================
    if (blk < 8) {
        // adjacency: 16 rows per block (one row per wave)
        int rr = blk * 16 + (t >> 6), l = t & 63;
        float s_loc = 0.f;
#pragma unroll
        for (int rep = 0; rep < 2; ++rep) {
            int j = l + rep * 64;
            float xv = P.rule_adj[rr * NR + j];
            float sg = 1.0f / (1.0f + expf(-xv));
            if (j == rr) sg = 0.0f;
            P.Aw[rr * NR + j] = sg;
            s_loc += sg;
        }
#pragma unroll
        for (int off = 32; off; off >>= 1) s_loc += __shfl_xor(s_loc, off);
        if (l == 0) P.rsum[rr] = s_loc;
        if (blk == 0) { P.gacc[t] = 0.f; P.gacc[1024 + t] = 0.f; }
    } else if (blk < 56) {
        // W2u[l2] = msg_W2[l2] @ upd_W1b[l2]; 16 rows/block, 4 rounds of 4
        int idx = blk - 8, l2 = idx / 16, rb = idx % 16;
        const float* A = P.msg_W2 + (size_t)l2 * HID * HID;
        const float* B = P.upd_W1 + (size_t)l2 * 2 * HID * HID + (size_t)HID * HID;
        float* C = P.W2u + (size_t)l2 * HID * HID;
        int col = t & 255, q = t >> 8;
        for (int rd = 0; rd < 4; ++rd) {
            int row0 = rb * 16 + rd * 4;
            sh.s.rows[q][col] = A[(size_t)(row0 + q) * HID + col];
            __syncthreads();
            float o[4];
            rows4_q(sh.s.rows, B, col, q, o);
#pragma unroll
            for (int ii = 0; ii < 4; ++ii) sh.s.part[q][ii][col] = o[ii];
            __syncthreads();
            C[(size_t)(row0 + q) * HID + col] =
                sh.s.part[0][q][col] + sh.s.part[1][q][col]
              + sh.s.part[2][q][col] + sh.s.part[3][q][col];
            __syncthreads();
        }
    } else if (blk < 59) {
        int l2 = blk - 56;
        if (t < 256) {
            const float* b2v = P.msg_b2 + l2 * HID;
            const float* Bm = P.upd_W1 + (size_t)l2 * 2 * HID * HID + (size_t)HID * HID;
            float acc = 0.f;
#pragma unroll 4
            for (int k = 0; k < HID; ++k) acc += b2v[k] * Bm[(size_t)k * HID + t];
            P.mb2u[l2 * HID + t] = acc;
        }
    } else if (blk < 67) {
        // h0[bb] = x[bb]@We + be
        int bb = blk - 59;
        if (t < NIN) sh.s.xs[t] = P.x[bb * NIN + t];
        __syncthreads();
        int col = t & 255, q = t >> 8;
        float acc = 0.f;
        int kb = q * 128;
#pragma unroll 8
        for (int k = 0; k < 128; ++k)
            acc += sh.s.xs[kb + k] * P.We[(size_t)(kb + k) * HID + col];
        sh.s.part[q][0][col] = acc;
        __syncthreads();
        if (q == 0)
            P.h0g[bb * HID + col] = sh.s.part[0][0][col] + sh.s.part[1][0][col]
                                  + sh.s.part[2][0][col] + sh.s.part[3][0][col]
                                  + P.be[col];
    } else if (blk < 71) {
        int idx4 = blk - 67;
        int base = idx4 * 16384;
        for (int i = t; i < 16384; i += 1024) {
            int o = base + i;
            P.mW1s[o] = P.msg_W1[o] + P.msg_W1[65536 + o];
        }
    } else {
        // prefetch weights -> warm L3
        int pfid = blk - 71, npf = 185;
        const float* arr[11] = {P.We, P.msg_W1, P.msg_W2, P.upd_W1, P.upd_W2,
                                P.Wq, P.Wk, P.Wv, P.Wo, P.ro_W1, P.ro_W2};
        const int n4[11] = {32768, 98304, 49152, 98304, 49152,
                            16384, 16384, 16384, 16384, 16384, 8192};
        float s = 0.f;
        for (int a2 = 0; a2 < 11; ++a2) {
            const float4* p4 = (const float4*)arr[a2];
            for (int i = pfid * 1024 + t; i < n4[a2]; i += npf * 1024) {
                float4 v = p4[i];
                s += v.x + v.y + v.z + v.w;
            }
        }
        if (s == 1.0e37f) P.scratch[pfid] = s;
    }
    sync_bar(gbar, 256);

    // ================= S1: per-batch head chain (sl==0 blocks) =================
    if (sl == 0) {
        int col = t & 255, q = t >> 8;
        if (t < 256) sh.m.h0s[t] = P.h0g[b * HID + t];
        __syncthreads();
        float o0 = gemv_q(sh.m.h0s, P.upd_W1, col, q);   // uW1a layer0
        float o1 = gemv_q(sh.m.h0s, P.mW1s, col, q);     // (mW1a+mW1b) layer0
        sh.m.part3[0][q][0][col] = o0;
        sh.m.part3[0][q][1][col] = o1;
        __syncthreads();
        if (q == 0) {
            float c0 = sh.m.part3[0][0][0][col] + sh.m.part3[0][1][0][col]
                     + sh.m.part3[0][2][0][col] + sh.m.part3[0][3][0][col];
            float pv = sh.m.part3[0][0][1][col] + sh.m.part3[0][1][1][col]
                     + sh.m.part3[0][2][1][col] + sh.m.part3[0][3][1][col]
                     + P.msg_b1[col];
            sh.m.u1s[0][col] = c0;                        // c0s
            sh.m.u1s[1][col] = fmaxf(pv, 0.0f);           // p0s
        }
        __syncthreads();
        float o2 = gemv_q(sh.m.u1s[1], P.W2u, col, q);    // W2u layer0
        sh.m.part3[0][q][0][col] = o2;
        __syncthreads();
        if (q == 0) {
            float c1 = sh.m.part3[0][0][0][col] + sh.m.part3[0][1][0][col]
                     + sh.m.part3[0][2][0][col] + sh.m.part3[0][3][0][col]
                     + P.mb2u[col];
            P.c0g[b * HID + col] = sh.m.u1s[0][col];
            P.c1g[b * HID + col] = c1;
        }
    }
    sync_bar(gbar, 256);

    // ================= S2: layer 0 =================
    layer0_stage(sh, P, b, i0, m0, t);
    sync_bar(gbar, 256);

    // ================= S3: layer 1 =================
    {
        const int l = 1;
        const float* mW1a2 = P.msg_W1 + (size_t)2 * 2 * HID * HID;
        const float* uW1a2 = P.upd_W1 + (size_t)2 * 2 * HID * HID;
        aggproj_stage(sh, P, b, i0, m0, t,
            P.aB, P.bbB, P.msg_b1 + (size_t)l * HID,
            P.p1B, P.W2u + (size_t)l * HID * HID, P.mb2u + l * HID,
            P.upd_b1 + (size_t)l * HID,
            P.upd_W2 + (size_t)l * HID * HID, P.upd_b2 + (size_t)l * HID,
            P.N0, P.ln_g + (size_t)l * HID, P.ln_b + (size_t)l * HID, P.N1,
            mW1a2, nullptr, P.aA,
            mW1a2 + (size_t)HID * HID, nullptr, P.bbA,
            uW1a2, nullptr, P.p1A);
    }
    sync_bar(gbar, 256);

    // ================= S4: layer 2 (-> q/k/v) =================
    {
        const int l = 2;
        aggproj_stage(sh, P, b, i0, m0, t,
            P.aA, P.bbA, P.msg_b1 + (size_t)l * HID,
            P.p1A, P.W2u + (size_t)l * HID * HID, P.mb2u + l * HID,
            P.upd_b1 + (size_t)l * HID,
            P.upd_W2 + (size_t)l * HID * HID, P.upd_b2 + (size_t)l * HID,
            P.N1, P.ln_g + (size_t)l * HID, P.ln_b + (size_t)l * HID, nullptr,
            P.Wq, P.bq, P.aB,
            P.Wk, P.bk, P.bbB,
            P.Wv, P.bv, P.p1B);
    }
    sync_bar(gbar, 256);

    // ================= S5: attention =================
    attn_stage(sh.a, P, b, sl, t);
    sync_bar(gbar, 256);

    // ================= S6: tail (sl==0 blocks) =================
    if (sl == 0) tail_stage(sh.tl, P, b, t);
}

// ---------------------------------------------------------------------------
extern "C" void kernel_launch(void* const* d_in, const int* in_sizes, int n_in,
                              void* d_out, int out_size, void* d_ws, size_t ws_size,
                              hipStream_t stream)
{
    KP P;
    P.x        = (const float*)d_in[0];
    P.We       = (const float*)d_in[1];
    P.be       = (const float*)d_in[2];
    P.msg_W1   = (const float*)d_in[3];
    P.msg_b1   = (const float*)d_in[4];
    P.msg_W2   = (const float*)d_in[5];
    P.msg_b2   = (const float*)d_in[6];
    P.upd_W1   = (const float*)d_in[7];
    P.upd_b1   = (const float*)d_in[8];
    P.upd_W2   = (const float*)d_in[9];
    P.upd_b2   = (const float*)d_in[10];
    P.ln_g     = (const float*)d_in[11];
    P.ln_b     = (const float*)d_in[12];
    P.rule_adj = (const float*)d_in[13];
    P.Wq       = (const float*)d_in[14];
    P.bq       = (const float*)d_in[15];
    P.Wk       = (const float*)d_in[16];
    P.bk       = (const float*)d_in[17];
    P.Wv       = (const float*)d_in[18];
    P.bv       = (const float*)d_in[19];
    P.Wo       = (const float*)d_in[20];
    P.bo       = (const float*)d_in[21];
    P.ro_W1    = (const float*)d_in[22];
    P.ro_b1    = (const float*)d_in[23];
    P.ro_W2    = (const float*)d_in[24];
    P.ro_b2    = (const float*)d_in[25];
    P.out      = (float*)d_out;

    float* b0 = (float*)d_ws;
    P.N0     = b0;  b0 += SZ;
    P.N1     = b0;  b0 += SZ;
    P.aB     = b0;  b0 += SZ;
    P.bbB    = b0;  b0 += SZ;
    P.p1B    = b0;  b0 += SZ;
    P.aA     = b0;  b0 += SZ;
    P.bbA    = b0;  b0 += SZ;
    P.p1A    = b0;  b0 += SZ;
    P.W2u    = b0;  b0 += 3 * HID * HID;
    P.mb2u   = b0;  b0 += 3 * HID;
    P.mW1s   = b0;  b0 += HID * HID;
    P.Aw     = b0;  b0 += NR * NR;
    P.rsum   = b0;  b0 += NR;
    P.h0g    = b0;  b0 += NB * HID;
    P.c0g    = b0;  b0 += NB * HID;
    P.c1g    = b0;  b0 += NB * HID;
    P.gacc   = b0;  b0 += NB * HID;
    P.scratch= b0;  b0 += 256;
    P.bars   = (unsigned*)b0; b0 += 256;

    // zero the device-barrier counter (graph-capturable memset)
    hipMemsetAsync((void*)P.bars, 0, 256 * sizeof(unsigned), stream);

    // single persistent kernel: grid == 256 CUs, 1 block/CU (all resident)
    mega_kernel<<<dim3(256), 1024, 0, stream>>>(P);
}

// Round 9
// 239.842 us; speedup vs baseline: 1.3492x; 1.3492x over previous
//
#include <hip/hip_runtime.h>
#include <math.h>

// Problem dims (fixed)
constexpr int NB  = 8;    // batch
constexpr int NR  = 128;  // rule nodes
constexpr int HID = 256;  // hidden
constexpr int NIN = 512;  // input dim
constexpr int DHD = 64;   // head dim
constexpr size_t SZ = (size_t)NB * NR * HID;  // 262144

struct KP {
    const float *x, *We, *be, *msg_W1, *msg_b1, *msg_W2, *msg_b2;
    const float *upd_W1, *upd_b1, *upd_W2, *upd_b2, *ln_g, *ln_b, *rule_adj;
    const float *Wq, *bq, *Wk, *bk, *Wv, *bv, *Wo, *bo, *ro_W1, *ro_b1, *ro_W2, *ro_b2;
    float* out;
    float *N0, *N1, *N2;                 // normalized h streams
    float *aB, *bbB, *p1B;               // proj set B (layer inputs / qkv)
    float *aA, *bbA, *p1A;               // proj set A
    float *W2u, *mb2u, *Aw, *rsum;       // W2u[l] = msg_W2[l]@upd_W1b[l]
    float *mW1s;                         // layer0: msg_W1a + msg_W1b
    float *h0g;
    float *c0g, *c1g;                    // per-batch layer0 head-chain results
    float *gacc;                         // tail mean accumulator [8,256]
    float *scratch;
    unsigned *cnt0;                      // setup producer counter
    unsigned *cntA;                      // per-batch attention-done counters [8]
};

// ---------------------------------------------------------------------------
// 64x64-tile fp32 GEMM core (K=256, BK=16) — used only in setup (W2u).
// ---------------------------------------------------------------------------
__device__ __forceinline__ void gemm_core(
    float (&As)[16][68], float (&Bs)[16][64], int m0, int n0,
    const float* __restrict__ A, const float* __restrict__ B,
    float (&acc)[4][4])
{
    int tid = threadIdx.x;
    int ty = tid >> 4, tx = tid & 15;
    int arow = tid >> 2, acol = (tid & 3) << 2;
    int brow = tid >> 4, bcol = (tid & 15) << 2;
    int m = m0 + arow;

    float4 av = *(const float4*)&A[(size_t)m * HID + acol];
    float4 bv = *(const float4*)&B[(size_t)brow * HID + n0 + bcol];

    for (int k0 = 0; k0 < HID; k0 += 16) {
        As[acol + 0][arow] = av.x;
        As[acol + 1][arow] = av.y;
        As[acol + 2][arow] = av.z;
        As[acol + 3][arow] = av.w;
        *(float4*)&Bs[brow][bcol] = bv;
        __syncthreads();
        if (k0 + 16 < HID) {
            av = *(const float4*)&A[(size_t)m * HID + k0 + 16 + acol];
            bv = *(const float4*)&B[(size_t)(k0 + 16 + brow) * HID + n0 + bcol];
        }
#pragma unroll
        for (int kk = 0; kk < 16; ++kk) {
            float4 af = *(const float4*)&As[kk][ty << 2];
            float4 bf = *(const float4*)&Bs[kk][tx << 2];
            float a_[4] = {af.x, af.y, af.z, af.w};
            float b_[4] = {bf.x, bf.y, bf.z, bf.w};
#pragma unroll
            for (int i = 0; i < 4; ++i)
#pragma unroll
                for (int j = 0; j < 4; ++j) acc[i][j] += a_[i] * b_[j];
        }
        __syncthreads();
    }
}

// ---------------------------------------------------------------------------
// Wave-split GEMV: y[0..255] = act(xs @ W + bias). W row-major [256,256].
// 256-thread blocks only.
// ---------------------------------------------------------------------------
__device__ __forceinline__ void gemv256w(
    const float* xs, const float* __restrict__ W,
    const float* __restrict__ bias, int relu, float* ys, float* red)
{
    int tid = threadIdx.x;
    int w = tid >> 6, l = tid & 63;
    float4 acc = {0.f, 0.f, 0.f, 0.f};
    const float* Wp = W + (size_t)(w * 64) * HID + l * 4;
    const float* xp = xs + w * 64;
#pragma unroll 16
    for (int kk = 0; kk < 64; ++kk) {
        float xv = xp[kk];
        float4 wv = *(const float4*)(Wp + (size_t)kk * HID);
        acc.x += xv * wv.x; acc.y += xv * wv.y;
        acc.z += xv * wv.z; acc.w += xv * wv.w;
    }
    *(float4*)&red[w * 256 + l * 4] = acc;
    __syncthreads();
    float v = red[tid] + red[256 + tid] + red[512 + tid] + red[768 + tid];
    if (bias) v += bias[tid];
    if (relu) v = fmaxf(v, 0.0f);
    ys[tid] = v;
    __syncthreads();
}

// ---------------------------------------------------------------------------
// k-quarter partial of rows4 matmul: col in [0,256), q in [0,4).
// ---------------------------------------------------------------------------
__device__ __forceinline__ void rows4_q(
    const float (&rows)[4][HID], const float* __restrict__ W,
    int col, int q, float o[4])
{
    o[0] = o[1] = o[2] = o[3] = 0.f;
    int kb = q * 64;
#pragma unroll 4
    for (int k0 = 0; k0 < 64; k0 += 4) {
        int k = kb + k0;
        float w0 = W[(size_t)(k + 0) * HID + col];
        float w1 = W[(size_t)(k + 1) * HID + col];
        float w2 = W[(size_t)(k + 2) * HID + col];
        float w3 = W[(size_t)(k + 3) * HID + col];
#pragma unroll
        for (int ii = 0; ii < 4; ++ii) {
            float4 rv = *(const float4*)&rows[ii][k];
            o[ii] += rv.x * w0 + rv.y * w1 + rv.z * w2 + rv.w * w3;
        }
    }
}

// Same partial for THREE weight matrices in one pass (loads pipeline 3x).
__device__ __forceinline__ void rows4_q3(
    const float (&rows)[4][HID],
    const float* __restrict__ W0, const float* __restrict__ W1,
    const float* __restrict__ W2m,
    int col, int q, float o[3][4])
{
#pragma unroll
    for (int p = 0; p < 3; ++p)
#pragma unroll
        for (int ii = 0; ii < 4; ++ii) o[p][ii] = 0.f;
    int kb = q * 64;
#pragma unroll 2
    for (int k0 = 0; k0 < 64; k0 += 4) {
        int k = kb + k0;
        float4 rv[4];
#pragma unroll
        for (int ii = 0; ii < 4; ++ii) rv[ii] = *(const float4*)&rows[ii][k];
        const float* Wp[3] = {W0, W1, W2m};
#pragma unroll
        for (int p = 0; p < 3; ++p) {
            const float* W = Wp[p];
            float w0 = W[(size_t)(k + 0) * HID + col];
            float w1 = W[(size_t)(k + 1) * HID + col];
            float w2 = W[(size_t)(k + 2) * HID + col];
            float w3 = W[(size_t)(k + 3) * HID + col];
#pragma unroll
            for (int ii = 0; ii < 4; ++ii)
                o[p][ii] += rv[ii].x * w0 + rv[ii].y * w1
                          + rv[ii].z * w2 + rv[ii].w * w3;
        }
    }
}

// ---------------------------------------------------------------------------
// Setup (merged): adjacency | W2u | mb2u | h0 | mW1s | head-chain | prefetch.
// Blocks 0-162 are producers (increment cnt0 when done); blocks 163-170 are
// the per-batch head-chain consumers (spin until all producers finished);
// 171-255 prefetch weights into L3. All 256 blocks co-resident (256 thr).
// ---------------------------------------------------------------------------
__global__ __launch_bounds__(256) void setup0_kernel(KP P) {
    __shared__ union {
        struct { float As[16][68]; float Bs[16][64]; } g;
        struct { float xs[NIN]; float part[8][32]; } e;
        struct { float h0s[HID]; float c0s[HID]; float p0s[HID]; float c1s[HID];
                 float red[1024]; } hc;
    } L;
    int blk = blockIdx.x;
    int t = threadIdx.x;

    if (blk < 32) {
        int rr = blk * 4 + (t >> 6);
        int l = t & 63;
        float s_loc = 0.f;
#pragma unroll
        for (int rep = 0; rep < 2; ++rep) {
            int j = l + rep * 64;
            float xv = P.rule_adj[rr * NR + j];
            float sg = 1.0f / (1.0f + expf(-xv));
            if (j == rr) sg = 0.0f;
            P.Aw[rr * NR + j] = sg;
            s_loc += sg;
        }
#pragma unroll
        for (int off = 32; off; off >>= 1) s_loc += __shfl_xor(s_loc, off);
        if (l == 0) P.rsum[rr] = s_loc;
    } else if (blk < 80) {
        int idx = blk - 32, l2 = idx >> 4, t16 = idx & 15;
        int m0 = (t16 >> 2) * 64, n0 = (t16 & 3) * 64;
        float acc[4][4] = {};
        gemm_core(L.g.As, L.g.Bs, m0, n0,
                  P.msg_W2 + (size_t)l2 * HID * HID,
                  P.upd_W1 + (size_t)l2 * 2 * HID * HID + (size_t)HID * HID,
                  acc);
        int ty = t >> 4, tx = t & 15;
        float* C = P.W2u + (size_t)l2 * HID * HID;
#pragma unroll
        for (int i = 0; i < 4; ++i) {
            int m = m0 + (ty << 2) + i, n = n0 + (tx << 2);
            float4 o = {acc[i][0], acc[i][1], acc[i][2], acc[i][3]};
            *(float4*)&C[(size_t)m * HID + n] = o;
        }
    } else if (blk < 83) {
        int l2 = blk - 80;
        const float* b2v = P.msg_b2 + l2 * HID;
        const float* Bm = P.upd_W1 + (size_t)l2 * 2 * HID * HID + (size_t)HID * HID;
        float acc = 0.f;
#pragma unroll 4
        for (int k = 0; k < HID; ++k) acc += b2v[k] * Bm[(size_t)k * HID + t];
        P.mb2u[l2 * HID + t] = acc;
    } else if (blk < 147) {
        // h0[b] = x[b]@We + be, distributed (8 b x 8 col-slices)
        int idx = blk - 83;
        int b = idx >> 3, s = idx & 7;
        L.e.xs[t]       = P.x[b * NIN + t];
        L.e.xs[256 + t] = P.x[b * NIN + 256 + t];
        __syncthreads();
        int c = t & 31, seg = t >> 5;
        int col = s * 32 + c;
        const float* Wp = P.We + (size_t)(seg * 64) * HID + col;
        const float* xp = L.e.xs + seg * 64;
        float acc = 0.f;
#pragma unroll 16
        for (int k = 0; k < 64; ++k) acc += xp[k] * Wp[(size_t)k * HID];
        L.e.part[seg][c] = acc;
        __syncthreads();
        if (t < 32) {
            float v = 0.f;
#pragma unroll
            for (int sg = 0; sg < 8; ++sg) v += L.e.part[sg][t];
            int cc = s * 32 + t;
            P.h0g[b * HID + cc] = v + P.be[cc];
        }
    } else if (blk < 163) {
        int base = (blk - 147) * 4096;
        for (int i = t; i < 4096; i += 256) {
            int o = base + i;
            P.mW1s[o] = P.msg_W1[o] + P.msg_W1[65536 + o];
        }
    } else if (blk < 171) {
        // head-chain consumer for batch b: wait for all 163 producers, then
        // c0 = h0@uW1a(0); p0 = relu(h0@mW1s + mb1(0)); c1 = p0@W2u(0)+mb2u(0)
        int b = blk - 163;
        if (t == 0) {
            while (atomicAdd(P.cnt0, 0u) < 163u) __builtin_amdgcn_s_sleep(8);
            __threadfence();
        }
        __syncthreads();
        L.hc.h0s[t] = P.h0g[b * HID + t];
        __syncthreads();
        gemv256w(L.hc.h0s, P.upd_W1, nullptr, 0, L.hc.c0s, L.hc.red);
        gemv256w(L.hc.h0s, P.mW1s, P.msg_b1, 1, L.hc.p0s, L.hc.red);
        gemv256w(L.hc.p0s, P.W2u, P.mb2u, 0, L.hc.c1s, L.hc.red);
        P.c0g[b * HID + t] = L.hc.c0s[t];
        P.c1g[b * HID + t] = L.hc.c1s[t];
    } else {
        // prefetch all weights -> warm L3 (poison evicts it every replay)
        int pfid = blk - 171, npf = 256 - 171;
        const float* arr[11] = {P.We, P.msg_W1, P.msg_W2, P.upd_W1, P.upd_W2,
                                P.Wq, P.Wk, P.Wv, P.Wo, P.ro_W1, P.ro_W2};
        const int n4[11] = {32768, 98304, 49152, 98304, 49152,
                            16384, 16384, 16384, 16384, 16384, 8192};
        float s = 0.f;
        for (int a = 0; a < 11; ++a) {
            const float4* p4 = (const float4*)arr[a];
            for (int i = pfid * 256 + t; i < n4[a]; i += npf * 256) {
                float4 v = p4[i];
                s += v.x + v.y + v.z + v.w;
            }
        }
        if (s == 1.0e37f) P.scratch[pfid] = s;  // keeps loads live
    }

    // producer completion signal
    if (blk < 163) {
        __syncthreads();
        if (t == 0) { __threadfence(); atomicAdd(P.cnt0, 1u); }
    }
}

// ---------------------------------------------------------------------------
// Layer 0 (head chain hoisted) + fused projection. 1024 threads, grid 256.
// Barrier phases: 5. All reduce phases use all 4 quarters (row=q).
// ---------------------------------------------------------------------------
__global__ __launch_bounds__(1024) void layer0p_kernel(KP P) {
    __shared__ float h0s[HID];
    __shared__ float u1s[4][HID];
    __shared__ float nrm[4][HID];
    __shared__ float part3[3][4][4][HID];
    __shared__ float sred[4][4][2];
    int blk = blockIdx.x;
    int m0 = blk * 4;
    int b = m0 >> 7, i0 = m0 & 127;
    int t = threadIdx.x;
    int col = t & 255, q = t >> 8;
    int w4 = (t >> 6) & 3, l = t & 63;

    // u1 rows: quarter q computes row q
    {
        float c0 = P.c0g[b * HID + col];
        float c1 = P.c1g[b * HID + col];
        if (q == 0) h0s[col] = P.h0g[b * HID + col];
        float ubv = P.upd_b1[col];
        u1s[q][col] = fmaxf(c0 + P.rsum[i0 + q] * c1 + ubv, 0.0f);
    }
    __syncthreads();                                       // (1)

    // uW2 partials
    {
        float o[4];
        rows4_q(u1s, P.upd_W2, col, q, o);
#pragma unroll
        for (int ii = 0; ii < 4; ++ii) part3[0][q][ii][col] = o[ii];
    }
    __syncthreads();                                       // (2)

    // v (row q) + LN wave partials
    float v;
    {
        float h0v = h0s[col] + P.upd_b2[col];
        v = part3[0][0][q][col] + part3[0][1][q][col]
          + part3[0][2][q][col] + part3[0][3][q][col] + h0v;
        float s = v, qq2 = v * v;
#pragma unroll
        for (int off = 32; off; off >>= 1) {
            s += __shfl_xor(s, off); qq2 += __shfl_xor(qq2, off);
        }
        if (l == 0) { sred[q][w4][0] = s; sred[q][w4][1] = qq2; }
    }
    __syncthreads();                                       // (3)
    {
        float ss  = sred[q][0][0] + sred[q][1][0] + sred[q][2][0] + sred[q][3][0];
        float qq2 = sred[q][0][1] + sred[q][1][1] + sred[q][2][1] + sred[q][3][1];
        float mu = ss * (1.0f / HID);
        float inv = rsqrtf(qq2 * (1.0f / HID) - mu * mu + 1e-5f);
        float nv = (v - mu) * inv * P.ln_g[col] + P.ln_b[col];
        nrm[q][col] = nv;
        P.N0[(size_t)(m0 + q) * HID + col] = nv;
    }
    __syncthreads();                                       // (4)

    // fused 3 projections to layer-1 inputs
    {
        const float* mW1a1 = P.msg_W1 + (size_t)1 * 2 * HID * HID;
        const float* uW1a1 = P.upd_W1 + (size_t)1 * 2 * HID * HID;
        float o3[3][4];
        rows4_q3(nrm, mW1a1, mW1a1 + (size_t)HID * HID, uW1a1, col, q, o3);
#pragma unroll
        for (int p = 0; p < 3; ++p)
#pragma unroll
            for (int ii = 0; ii < 4; ++ii) part3[p][q][ii][col] = o3[p][ii];
    }
    __syncthreads();                                       // (5)
    if (q < 3) {
        float* po = (q == 0) ? P.aB : (q == 1) ? P.bbB : P.p1B;
#pragma unroll
        for (int ii = 0; ii < 4; ++ii) {
            float s = part3[q][0][ii][col] + part3[q][1][ii][col]
                    + part3[q][2][ii][col] + part3[q][3][ii][col];
            po[(size_t)(m0 + ii) * HID + col] = s;
        }
    }
}

// ---------------------------------------------------------------------------
// Fused aggregate + u1 + resid + LN + fused next-layer projection.
// 1024 threads, grid 256. Barrier phases: 9; all-quarter reduces.
// ---------------------------------------------------------------------------
__global__ __launch_bounds__(1024) void aggproj_kernel(
    const float* __restrict__ a, const float* __restrict__ bbv,
    const float* __restrict__ mb1, const float* __restrict__ Aw,
    const float* __restrict__ rsumv,
    const float* __restrict__ P1, const float* __restrict__ W2u,
    const float* __restrict__ mb2u, const float* __restrict__ ub1,
    const float* __restrict__ uW2, const float* __restrict__ ub2,
    const float* __restrict__ Nprev, const float* __restrict__ lng,
    const float* __restrict__ lnb, float* __restrict__ Nout,
    const float* __restrict__ pw0, const float* __restrict__ pb0, float* __restrict__ o0,
    const float* __restrict__ pw1, const float* __restrict__ pb1, float* __restrict__ o1,
    const float* __restrict__ pw2, const float* __restrict__ pb2, float* __restrict__ o2,
    float* __restrict__ gzero)
{
    __shared__ float ap[4][HID];
    __shared__ float u1s[4][HID];
    __shared__ float nrm[4][HID];
    __shared__ float awr[4][NR];
    __shared__ float part3[3][4][4][HID];
    __shared__ float sred[4][4][2];
    int blk = blockIdx.x;
    int b  = blk >> 5;
    int i0 = (blk & 31) * 4;
    int m0 = b * NR + i0;
    int t  = threadIdx.x;
    int col = t & 255, q = t >> 8;
    int w4 = (t >> 6) & 3, l = t & 63;

    if (gzero && blk == 0 && q == 0) {
#pragma unroll
        for (int i = 0; i < 8; ++i) gzero[i * 256 + col] = 0.f;
    }

    // stage adjacency rows: threads 0..511 cover 4x128
    if (t < 512) awr[t >> 7][t & 127] = Aw[(i0 + (t >> 7)) * NR + (t & 127)];

    float bias = mb1[col];
    float ai[4];
#pragma unroll
    for (int ii = 0; ii < 4; ++ii)
        ai[ii] = a[(size_t)(m0 + ii) * HID + col] + bias;
    __syncthreads();                                       // (1)

    // aggregate partials, j-quarter: q sums j in [q*32, q*32+32)
    {
        float acc[4] = {0.f, 0.f, 0.f, 0.f};
        const float* bbb = &bbv[(size_t)b * NR * HID + col];
        int jb = q * 32;
#pragma unroll 4
        for (int j = 0; j < 32; ++j) {
            float bj = bbb[(size_t)(jb + j) * HID];
#pragma unroll
            for (int ii = 0; ii < 4; ++ii) {
                float pre = fmaxf(ai[ii] + bj, 0.0f);
                acc[ii] += awr[ii][jb + j] * pre;
            }
        }
#pragma unroll
        for (int ii = 0; ii < 4; ++ii) part3[0][q][ii][col] = acc[ii];
    }
    __syncthreads();                                       // (2)
    ap[q][col] = part3[0][0][q][col] + part3[0][1][q][col]
               + part3[0][2][q][col] + part3[0][3][q][col];
    __syncthreads();                                       // (3)

    // W2u pass -> u1
    {
        float o[4];
        rows4_q(ap, W2u, col, q, o);
#pragma unroll
        for (int ii = 0; ii < 4; ++ii) part3[0][q][ii][col] = o[ii];
    }
    __syncthreads();                                       // (4)
    {
        float w2f = part3[0][0][q][col] + part3[0][1][q][col]
                  + part3[0][2][q][col] + part3[0][3][q][col];
        float vv = w2f + P1[(size_t)(m0 + q) * HID + col]
                 + rsumv[i0 + q] * mb2u[col] + ub1[col];
        u1s[q][col] = fmaxf(vv, 0.0f);
    }
    __syncthreads();                                       // (5)

    // uW2 -> v, LN
    {
        float o[4];
        rows4_q(u1s, uW2, col, q, o);
#pragma unroll
        for (int ii = 0; ii < 4; ++ii) part3[0][q][ii][col] = o[ii];
    }
    __syncthreads();                                       // (6)
    float v;
    {
        float uf = part3[0][0][q][col] + part3[0][1][q][col]
                 + part3[0][2][q][col] + part3[0][3][q][col];
        v = Nprev[(size_t)(m0 + q) * HID + col] + uf + ub2[col];
        float s = v, qq2 = v * v;
#pragma unroll
        for (int off = 32; off; off >>= 1) {
            s += __shfl_xor(s, off); qq2 += __shfl_xor(qq2, off);
        }
        if (l == 0) { sred[q][w4][0] = s; sred[q][w4][1] = qq2; }
    }
    __syncthreads();                                       // (7)
    {
        float ss  = sred[q][0][0] + sred[q][1][0] + sred[q][2][0] + sred[q][3][0];
        float qq2 = sred[q][0][1] + sred[q][1][1] + sred[q][2][1] + sred[q][3][1];
        float mu = ss * (1.0f / HID);
        float inv = rsqrtf(qq2 * (1.0f / HID) - mu * mu + 1e-5f);
        float nv = (v - mu) * inv * lng[col] + lnb[col];
        nrm[q][col] = nv;
        Nout[(size_t)(m0 + q) * HID + col] = nv;
    }
    __syncthreads();                                       // (8)

    // fused 3 projections
    {
        float o3[3][4];
        rows4_q3(nrm, pw0, pw1, pw2, col, q, o3);
#pragma unroll
        for (int p = 0; p < 3; ++p)
#pragma unroll
            for (int ii = 0; ii < 4; ++ii) part3[p][q][ii][col] = o3[p][ii];
    }
    __syncthreads();                                       // (9)
    if (q < 3) {
        const float* pb = (q == 0) ? pb0 : (q == 1) ? pb1 : pb2;
        float* po = (q == 0) ? o0 : (q == 1) ? o1 : o2;
        float pbv = pb ? pb[col] : 0.f;
#pragma unroll
        for (int ii = 0; ii < 4; ++ii) {
            float s = part3[q][0][ii][col] + part3[q][1][ii][col]
                    + part3[q][2][ii][col] + part3[q][3][ii][col] + pbv;
            po[(size_t)(m0 + ii) * HID + col] = s;
        }
    }
}

// ---------------------------------------------------------------------------
// Fused attention + mean + (last block per batch) tail.
// blk = bh*8 + ig; 16 q-rows per block, one (b,head). 256 threads.
// ---------------------------------------------------------------------------
__global__ __launch_bounds__(256) void attention_kernel(KP P)
{
    __shared__ union {
        struct { float KhT[64][128]; float S[16][128]; float qs[16][64]; } a;
        struct { float v0[HID]; float v1[HID]; float v2[HID]; float red[1024]; } tl;
    } L;
    __shared__ int last;
    int blk = blockIdx.x;
    int bh = blk >> 3, ig = blk & 7;
    int b = bh >> 2, hd = bh & 3;
    int i0 = ig * 16;
    int t = threadIdx.x;
    const float* qg = P.aB  + ((size_t)b * NR) * HID + hd * DHD;
    const float* kg = P.bbB + ((size_t)b * NR) * HID + hd * DHD;
    const float* vg = P.p1B + ((size_t)b * NR) * HID + hd * DHD;

    {   // stage K^T (conflict-free: bank = j%32, 2 lanes/bank)
        int j = t >> 1, half = t & 1;
        const float* krow = kg + (size_t)j * HID + half * 32;
#pragma unroll
        for (int c = 0; c < 32; c += 4) {
            float4 kv = *(const float4*)(krow + c);
            L.a.KhT[half * 32 + c + 0][j] = kv.x;
            L.a.KhT[half * 32 + c + 1][j] = kv.y;
            L.a.KhT[half * 32 + c + 2][j] = kv.z;
            L.a.KhT[half * 32 + c + 3][j] = kv.w;
        }
    }
    {   // stage q rows
        int ii = t >> 4, d0 = (t & 15) * 4;
        *(float4*)&L.a.qs[ii][d0] = *(const float4*)(qg + (size_t)(i0 + ii) * HID + d0);
    }
    __syncthreads();
    {   // scores
        int j = t & 127, ii2 = t >> 7;
        float acc[8] = {0.f,0.f,0.f,0.f,0.f,0.f,0.f,0.f};
#pragma unroll 4
        for (int d = 0; d < 64; ++d) {
            float kv = L.a.KhT[d][j];
#pragma unroll
            for (int ii = 0; ii < 8; ++ii) acc[ii] += L.a.qs[ii2 * 8 + ii][d] * kv;
        }
#pragma unroll
        for (int ii = 0; ii < 8; ++ii) L.a.S[ii2 * 8 + ii][j] = acc[ii] * 0.125f;
    }
    __syncthreads();
    {   // softmax per row
        int w = t >> 6, l = t & 63;
#pragma unroll
        for (int r = w * 4; r < w * 4 + 4; ++r) {
            float e0 = L.a.S[r][l], e1 = L.a.S[r][l + 64];
            float mx = fmaxf(e0, e1);
#pragma unroll
            for (int off = 32; off; off >>= 1) mx = fmaxf(mx, __shfl_xor(mx, off));
            e0 = expf(e0 - mx); e1 = expf(e1 - mx);
            float sm = e0 + e1;
#pragma unroll
            for (int off = 32; off; off >>= 1) sm += __shfl_xor(sm, off);
            float inv = 1.0f / sm;
            L.a.S[r][l] = e0 * inv; L.a.S[r][l + 64] = e1 * inv;
        }
    }
    __syncthreads();
    {   // PV + row-sum into gacc
        int d = t & 63, ir = t >> 6;
        float accv[4] = {0.f, 0.f, 0.f, 0.f};
        const float* vp = vg + d;
#pragma unroll 8
        for (int j = 0; j < NR; ++j) {
            float vv = vp[(size_t)j * HID];
#pragma unroll
            for (int p = 0; p < 4; ++p) accv[p] += L.a.S[p * 4 + ir][j] * vv;
        }
        float s = accv[0] + accv[1] + accv[2] + accv[3];
        atomicAdd(&P.gacc[b * HID + hd * DHD + d], s);
    }

    // ---- last-block-per-batch runs the tail (zero-spin reduction gate) ----
    __threadfence();
    __syncthreads();
    if (t == 0) {
        unsigned old = atomicAdd(&P.cntA[b], 1u);
        last = (old == 31u) ? 1 : 0;
    }
    __syncthreads();
    if (!last) return;
    __threadfence();                     // acquire: see all 32 blocks' gacc adds
    __syncthreads();                     // attention shared now dead; reuse as tail

    int w = t >> 6, l = t & 63;
    L.tl.v0[t] = P.gacc[b * HID + t] * (1.0f / NR);
    __syncthreads();
    gemv256w(L.tl.v0, P.Wo, P.bo, 0, L.tl.v1, L.tl.red);
    gemv256w(L.tl.v1, P.ro_W1, P.ro_b1, 1, L.tl.v2, L.tl.red);

    {   // logits: N=128; lane l -> outputs 2l,2l+1; wave w -> K quarter
        float2 acc = {0.f, 0.f};
        const float* Wp = P.ro_W2 + (size_t)(w * 64) * NR + l * 2;
        const float* xp = L.tl.v2 + w * 64;
#pragma unroll 8
        for (int kk = 0; kk < 64; ++kk) {
            float xv = xp[kk];
            float2 wv = *(const float2*)(Wp + (size_t)kk * NR);
            acc.x += xv * wv.x; acc.y += xv * wv.y;
        }
        *(float2*)&L.tl.red[w * 128 + l * 2] = acc;
        __syncthreads();
    }
    float logit = -1e30f;
    if (t < NR) logit = L.tl.red[t] + L.tl.red[128 + t] + L.tl.red[256 + t]
                      + L.tl.red[384 + t] + P.ro_b2[t];
    __syncthreads();
    float m = logit;
#pragma unroll
    for (int off = 32; off; off >>= 1) m = fmaxf(m, __shfl_xor(m, off));
    if (l == 0) L.tl.red[w] = m;
    __syncthreads();
    m = fmaxf(L.tl.red[0], L.tl.red[1]);
    float e = (t < NR) ? expf(logit - m) : 0.0f;
    float ssum = e;
#pragma unroll
    for (int off = 32; off; off >>= 1) ssum += __shfl_xor(ssum, off);
    if (l == 0) L.tl.red[4 + w] = ssum;
    __syncthreads();
    float tot = L.tl.red[4] + L.tl.red[5];
    if (t < NR) P.out[b * NR + t] = e / tot;
}

// ---------------------------------------------------------------------------
extern "C" void kernel_launch(void* const* d_in, const int* in_sizes, int n_in,
                              void* d_out, int out_size, void* d_ws, size_t ws_size,
                              hipStream_t stream)
{
    KP P;
    P.x        = (const float*)d_in[0];
    P.We       = (const float*)d_in[1];
    P.be       = (const float*)d_in[2];
    P.msg_W1   = (const float*)d_in[3];
    P.msg_b1   = (const float*)d_in[4];
    P.msg_W2   = (const float*)d_in[5];
    P.msg_b2   = (const float*)d_in[6];
    P.upd_W1   = (const float*)d_in[7];
    P.upd_b1   = (const float*)d_in[8];
    P.upd_W2   = (const float*)d_in[9];
    P.upd_b2   = (const float*)d_in[10];
    P.ln_g     = (const float*)d_in[11];
    P.ln_b     = (const float*)d_in[12];
    P.rule_adj = (const float*)d_in[13];
    P.Wq       = (const float*)d_in[14];
    P.bq       = (const float*)d_in[15];
    P.Wk       = (const float*)d_in[16];
    P.bk       = (const float*)d_in[17];
    P.Wv       = (const float*)d_in[18];
    P.bv       = (const float*)d_in[19];
    P.Wo       = (const float*)d_in[20];
    P.bo       = (const float*)d_in[21];
    P.ro_W1    = (const float*)d_in[22];
    P.ro_b1    = (const float*)d_in[23];
    P.ro_W2    = (const float*)d_in[24];
    P.ro_b2    = (const float*)d_in[25];
    P.out      = (float*)d_out;

    float* b0 = (float*)d_ws;
    P.N0     = b0;  b0 += SZ;
    P.N1     = b0;  b0 += SZ;
    P.N2     = b0;  b0 += SZ;
    P.aB     = b0;  b0 += SZ;
    P.bbB    = b0;  b0 += SZ;
    P.p1B    = b0;  b0 += SZ;
    P.aA     = b0;  b0 += SZ;
    P.bbA    = b0;  b0 += SZ;
    P.p1A    = b0;  b0 += SZ;
    P.W2u    = b0;  b0 += 3 * HID * HID;
    P.mb2u   = b0;  b0 += 3 * HID;
    P.mW1s   = b0;  b0 += HID * HID;
    P.Aw     = b0;  b0 += NR * NR;
    P.rsum   = b0;  b0 += NR;
    P.h0g    = b0;  b0 += NB * HID;
    P.c0g    = b0;  b0 += NB * HID;
    P.c1g    = b0;  b0 += NB * HID;
    P.gacc   = b0;  b0 += NB * HID;
    P.scratch= b0;  b0 += 256;
    P.cnt0   = (unsigned*)b0;      // 1 counter
    P.cntA   = (unsigned*)b0 + 8;  // 8 counters
    b0 += 64;

    // zero the gate counters (graph-capturable)
    hipMemsetAsync((void*)P.cnt0, 0, 64 * sizeof(float), stream);

    // 1. setup (merged): adj | W2u | mb2u | h0 | mW1s | head chain | prefetch
    setup0_kernel<<<dim3(256), 256, 0, stream>>>(P);

    // 2. layer 0 (head chain hoisted) + projection to layer-1 inputs (set B)
    layer0p_kernel<<<dim3(256), 1024, 0, stream>>>(P);

    // 3. layer 1: agg + resid + LN + projection to layer-2 inputs (set A)
    {
        const int l = 1;
        const float* mW1a2 = P.msg_W1 + (size_t)2 * 2 * HID * HID;
        const float* uW1a2 = P.upd_W1 + (size_t)2 * 2 * HID * HID;
        aggproj_kernel<<<dim3(256), 1024, 0, stream>>>(
            P.aB, P.bbB, P.msg_b1 + (size_t)l * HID, P.Aw, P.rsum,
            P.p1B, P.W2u + (size_t)l * HID * HID, P.mb2u + l * HID,
            P.upd_b1 + (size_t)l * HID,
            P.upd_W2 + (size_t)l * HID * HID, P.upd_b2 + (size_t)l * HID,
            P.N0, P.ln_g + (size_t)l * HID, P.ln_b + (size_t)l * HID, P.N1,
            mW1a2, nullptr, P.aA,
            mW1a2 + (size_t)HID * HID, nullptr, P.bbA,
            uW1a2, nullptr, P.p1A,
            nullptr);
    }

    // 4. layer 2: agg + resid + LN + projection to q/k/v (set B); zeroes gacc
    {
        const int l = 2;
        aggproj_kernel<<<dim3(256), 1024, 0, stream>>>(
            P.aA, P.bbA, P.msg_b1 + (size_t)l * HID, P.Aw, P.rsum,
            P.p1A, P.W2u + (size_t)l * HID * HID, P.mb2u + l * HID,
            P.upd_b1 + (size_t)l * HID,
            P.upd_W2 + (size_t)l * HID * HID, P.upd_b2 + (size_t)l * HID,
            P.N1, P.ln_g + (size_t)l * HID, P.ln_b + (size_t)l * HID, P.N2,
            P.Wq, P.bq, P.aB,
            P.Wk, P.bk, P.bbB,
            P.Wv, P.bv, P.p1B,
            P.gacc);
    }

    // 5. attention + mean + inline tail (last block per batch)
    attention_kernel<<<dim3(256), 256, 0, stream>>>(P);
}

// Round 10
// 222.983 us; speedup vs baseline: 1.4512x; 1.0756x over previous
//
#include <hip/hip_runtime.h>
#include <math.h>

// Problem dims (fixed)
constexpr int NB  = 8;    // batch
constexpr int NR  = 128;  // rule nodes
constexpr int HID = 256;  // hidden
constexpr int NIN = 512;  // input dim
constexpr int DHD = 64;   // head dim
constexpr size_t SZ = (size_t)NB * NR * HID;  // 262144

struct KP {
    const float *x, *We, *be, *msg_W1, *msg_b1, *msg_W2, *msg_b2;
    const float *upd_W1, *upd_b1, *upd_W2, *upd_b2, *ln_g, *ln_b, *rule_adj;
    const float *Wq, *bq, *Wk, *bk, *Wv, *bv, *Wo, *bo, *ro_W1, *ro_b1, *ro_W2, *ro_b2;
    float* out;
    float *N0, *N1, *N2;                 // normalized h streams
    float *aB, *bbB, *p1B;               // proj set B (layer inputs / qkv)
    float *aA, *bbA, *p1A;               // proj set A
    float *W2u, *mb2u, *Aw, *rsum;       // W2u[l] = msg_W2[l]@upd_W1b[l]
    float *mW1s;                         // layer0: msg_W1a + msg_W1b
    float *h0g;
    float *c0g, *c1g;                    // per-batch layer0 head-chain results
    float *gacc;                         // tail mean accumulator [8,256]
    float *scratch;
};

// ---------------------------------------------------------------------------
// 64x64-tile fp32 GEMM core (K=256, BK=16) — used only in setup (W2u).
// ---------------------------------------------------------------------------
__device__ __forceinline__ void gemm_core(
    float (&As)[16][68], float (&Bs)[16][64], int m0, int n0,
    const float* __restrict__ A, const float* __restrict__ B,
    float (&acc)[4][4])
{
    int tid = threadIdx.x;
    int ty = tid >> 4, tx = tid & 15;
    int arow = tid >> 2, acol = (tid & 3) << 2;
    int brow = tid >> 4, bcol = (tid & 15) << 2;
    int m = m0 + arow;

    float4 av = *(const float4*)&A[(size_t)m * HID + acol];
    float4 bv = *(const float4*)&B[(size_t)brow * HID + n0 + bcol];

    for (int k0 = 0; k0 < HID; k0 += 16) {
        As[acol + 0][arow] = av.x;
        As[acol + 1][arow] = av.y;
        As[acol + 2][arow] = av.z;
        As[acol + 3][arow] = av.w;
        *(float4*)&Bs[brow][bcol] = bv;
        __syncthreads();
        if (k0 + 16 < HID) {
            av = *(const float4*)&A[(size_t)m * HID + k0 + 16 + acol];
            bv = *(const float4*)&B[(size_t)(k0 + 16 + brow) * HID + n0 + bcol];
        }
#pragma unroll
        for (int kk = 0; kk < 16; ++kk) {
            float4 af = *(const float4*)&As[kk][ty << 2];
            float4 bf = *(const float4*)&Bs[kk][tx << 2];
            float a_[4] = {af.x, af.y, af.z, af.w};
            float b_[4] = {bf.x, bf.y, bf.z, bf.w};
#pragma unroll
            for (int i = 0; i < 4; ++i)
#pragma unroll
                for (int j = 0; j < 4; ++j) acc[i][j] += a_[i] * b_[j];
        }
        __syncthreads();
    }
}

// ---------------------------------------------------------------------------
// Wave-split GEMV: y[0..255] = act(xs @ W + bias). W row-major [256,256].
// ---------------------------------------------------------------------------
__device__ __forceinline__ void gemv256w(
    const float* xs, const float* __restrict__ W,
    const float* __restrict__ bias, int relu, float* ys, float* red)
{
    int tid = threadIdx.x;
    int w = tid >> 6, l = tid & 63;
    float4 acc = {0.f, 0.f, 0.f, 0.f};
    const float* Wp = W + (size_t)(w * 64) * HID + l * 4;
    const float* xp = xs + w * 64;
#pragma unroll 16
    for (int kk = 0; kk < 64; ++kk) {
        float xv = xp[kk];
        float4 wv = *(const float4*)(Wp + (size_t)kk * HID);
        acc.x += xv * wv.x; acc.y += xv * wv.y;
        acc.z += xv * wv.z; acc.w += xv * wv.w;
    }
    *(float4*)&red[w * 256 + l * 4] = acc;
    __syncthreads();
    float v = red[tid] + red[256 + tid] + red[512 + tid] + red[768 + tid];
    if (bias) v += bias[tid];
    if (relu) v = fmaxf(v, 0.0f);
    ys[tid] = v;
    __syncthreads();
}

// ---------------------------------------------------------------------------
// k-quarter partial of rows4 matmul: col in [0,256), q in [0,4).
// ---------------------------------------------------------------------------
__device__ __forceinline__ void rows4_q(
    const float (&rows)[4][HID], const float* __restrict__ W,
    int col, int q, float o[4])
{
    o[0] = o[1] = o[2] = o[3] = 0.f;
    int kb = q * 64;
#pragma unroll 4
    for (int k0 = 0; k0 < 64; k0 += 4) {
        int k = kb + k0;
        float w0 = W[(size_t)(k + 0) * HID + col];
        float w1 = W[(size_t)(k + 1) * HID + col];
        float w2 = W[(size_t)(k + 2) * HID + col];
        float w3 = W[(size_t)(k + 3) * HID + col];
#pragma unroll
        for (int ii = 0; ii < 4; ++ii) {
            float4 rv = *(const float4*)&rows[ii][k];
            o[ii] += rv.x * w0 + rv.y * w1 + rv.z * w2 + rv.w * w3;
        }
    }
}

// Same partial for THREE weight matrices in one pass (loads pipeline 3x).
__device__ __forceinline__ void rows4_q3(
    const float (&rows)[4][HID],
    const float* __restrict__ W0, const float* __restrict__ W1,
    const float* __restrict__ W2m,
    int col, int q, float o[3][4])
{
#pragma unroll
    for (int p = 0; p < 3; ++p)
#pragma unroll
        for (int ii = 0; ii < 4; ++ii) o[p][ii] = 0.f;
    int kb = q * 64;
#pragma unroll 2
    for (int k0 = 0; k0 < 64; k0 += 4) {
        int k = kb + k0;
        float4 rv[4];
#pragma unroll
        for (int ii = 0; ii < 4; ++ii) rv[ii] = *(const float4*)&rows[ii][k];
        const float* Wp[3] = {W0, W1, W2m};
#pragma unroll
        for (int p = 0; p < 3; ++p) {
            const float* W = Wp[p];
            float w0 = W[(size_t)(k + 0) * HID + col];
            float w1 = W[(size_t)(k + 1) * HID + col];
            float w2 = W[(size_t)(k + 2) * HID + col];
            float w3 = W[(size_t)(k + 3) * HID + col];
#pragma unroll
            for (int ii = 0; ii < 4; ++ii)
                o[p][ii] += rv[ii].x * w0 + rv[ii].y * w1
                          + rv[ii].z * w2 + rv[ii].w * w3;
        }
    }
}

// ---------------------------------------------------------------------------
// Setup: adjacency | W2u[l]=mW2[l]@uW1b[l] | mb2u | h0 | mW1s | prefetch.
// ---------------------------------------------------------------------------
__global__ __launch_bounds__(256) void setup0_kernel(KP P) {
    __shared__ union {
        struct { float As[16][68]; float Bs[16][64]; } g;
        struct { float xs[NIN]; float part[8][32]; } e;
    } L;
    int blk = blockIdx.x;
    int t = threadIdx.x;

    if (blk < 32) {
        int rr = blk * 4 + (t >> 6);
        int l = t & 63;
        float s_loc = 0.f;
#pragma unroll
        for (int rep = 0; rep < 2; ++rep) {
            int j = l + rep * 64;
            float xv = P.rule_adj[rr * NR + j];
            float sg = 1.0f / (1.0f + expf(-xv));
            if (j == rr) sg = 0.0f;
            P.Aw[rr * NR + j] = sg;
            s_loc += sg;
        }
#pragma unroll
        for (int off = 32; off; off >>= 1) s_loc += __shfl_xor(s_loc, off);
        if (l == 0) P.rsum[rr] = s_loc;
    } else if (blk < 80) {
        int idx = blk - 32, l2 = idx >> 4, t16 = idx & 15;
        int m0 = (t16 >> 2) * 64, n0 = (t16 & 3) * 64;
        float acc[4][4] = {};
        gemm_core(L.g.As, L.g.Bs, m0, n0,
                  P.msg_W2 + (size_t)l2 * HID * HID,
                  P.upd_W1 + (size_t)l2 * 2 * HID * HID + (size_t)HID * HID,
                  acc);
        int ty = t >> 4, tx = t & 15;
        float* C = P.W2u + (size_t)l2 * HID * HID;
#pragma unroll
        for (int i = 0; i < 4; ++i) {
            int m = m0 + (ty << 2) + i, n = n0 + (tx << 2);
            float4 o = {acc[i][0], acc[i][1], acc[i][2], acc[i][3]};
            *(float4*)&C[(size_t)m * HID + n] = o;
        }
    } else if (blk < 83) {
        int l2 = blk - 80;
        const float* b2v = P.msg_b2 + l2 * HID;
        const float* Bm = P.upd_W1 + (size_t)l2 * 2 * HID * HID + (size_t)HID * HID;
        float acc = 0.f;
#pragma unroll 4
        for (int k = 0; k < HID; ++k) acc += b2v[k] * Bm[(size_t)k * HID + t];
        P.mb2u[l2 * HID + t] = acc;
    } else if (blk < 147) {
        // h0[b] = x[b]@We + be, distributed (8 b x 8 col-slices)
        int idx = blk - 83;
        int b = idx >> 3, s = idx & 7;
        L.e.xs[t]       = P.x[b * NIN + t];
        L.e.xs[256 + t] = P.x[b * NIN + 256 + t];
        __syncthreads();
        int c = t & 31, seg = t >> 5;
        int col = s * 32 + c;
        const float* Wp = P.We + (size_t)(seg * 64) * HID + col;
        const float* xp = L.e.xs + seg * 64;
        float acc = 0.f;
#pragma unroll 16
        for (int k = 0; k < 64; ++k) acc += xp[k] * Wp[(size_t)k * HID];
        L.e.part[seg][c] = acc;
        __syncthreads();
        if (t < 32) {
            float v = 0.f;
#pragma unroll
            for (int sg = 0; sg < 8; ++sg) v += L.e.part[sg][t];
            int cc = s * 32 + t;
            P.h0g[b * HID + cc] = v + P.be[cc];
        }
    } else if (blk < 163) {
        int base = (blk - 147) * 4096;
        for (int i = t; i < 4096; i += 256) {
            int o = base + i;
            P.mW1s[o] = P.msg_W1[o] + P.msg_W1[65536 + o];
        }
    } else {
        // prefetch all weights -> warm L3 (poison evicts it every replay)
        int pfid = blk - 163, npf = 256 - 163;
        const float* arr[11] = {P.We, P.msg_W1, P.msg_W2, P.upd_W1, P.upd_W2,
                                P.Wq, P.Wk, P.Wv, P.Wo, P.ro_W1, P.ro_W2};
        const int n4[11] = {32768, 98304, 49152, 98304, 49152,
                            16384, 16384, 16384, 16384, 16384, 8192};
        float s = 0.f;
        for (int a = 0; a < 11; ++a) {
            const float4* p4 = (const float4*)arr[a];
            for (int i = pfid * 256 + t; i < n4[a]; i += npf * 256) {
                float4 v = p4[i];
                s += v.x + v.y + v.z + v.w;
            }
        }
        if (s == 1.0e37f) P.scratch[pfid] = s;  // keeps loads live
    }
}

// ---------------------------------------------------------------------------
// Setup stage 2: per-batch layer-0 head chain (depends only on b).
// ---------------------------------------------------------------------------
__global__ __launch_bounds__(256) void setup1_kernel(KP P) {
    __shared__ float h0s[HID], c0s[HID], p0s[HID], c1s[HID];
    __shared__ float red[1024];
    int b = blockIdx.x;
    int t = threadIdx.x;
    h0s[t] = P.h0g[b * HID + t];
    __syncthreads();
    gemv256w(h0s, P.upd_W1, nullptr, 0, c0s, red);        // uW1a, layer 0
    gemv256w(h0s, P.mW1s, P.msg_b1, 1, p0s, red);         // relu(h0@(W1a+W1b)+b1)
    gemv256w(p0s, P.W2u, P.mb2u, 0, c1s, red);            // W2u, layer 0
    P.c0g[b * HID + t] = c0s[t];
    P.c1g[b * HID + t] = c1s[t];
}

// ---------------------------------------------------------------------------
// Layer 0 (head chain hoisted) + fused projection. 1024 threads, grid 256.
// Barrier phases: 5. All reduce phases use all 4 quarters (row=q).
// ---------------------------------------------------------------------------
__global__ __launch_bounds__(1024) void layer0p_kernel(KP P) {
    __shared__ float h0s[HID];
    __shared__ float u1s[4][HID];
    __shared__ float nrm[4][HID];
    __shared__ float part3[3][4][4][HID];
    __shared__ float sred[4][4][2];
    int blk = blockIdx.x;
    int m0 = blk * 4;
    int b = m0 >> 7, i0 = m0 & 127;
    int t = threadIdx.x;
    int col = t & 255, q = t >> 8;
    int w4 = (t >> 6) & 3, l = t & 63;

    // u1 rows: quarter q computes row q (no partials needed)
    {
        float c0 = P.c0g[b * HID + col];
        float c1 = P.c1g[b * HID + col];
        if (q == 0) h0s[col] = P.h0g[b * HID + col];
        float ubv = P.upd_b1[col];
        u1s[q][col] = fmaxf(c0 + P.rsum[i0 + q] * c1 + ubv, 0.0f);
    }
    __syncthreads();                                       // (1)

    // uW2 partials
    {
        float o[4];
        rows4_q(u1s, P.upd_W2, col, q, o);
#pragma unroll
        for (int ii = 0; ii < 4; ++ii) part3[0][q][ii][col] = o[ii];
    }
    __syncthreads();                                       // (2)

    // v (row q) + LN wave partials
    float v;
    {
        float h0v = h0s[col] + P.upd_b2[col];
        v = part3[0][0][q][col] + part3[0][1][q][col]
          + part3[0][2][q][col] + part3[0][3][q][col] + h0v;
        float s = v, qq2 = v * v;
#pragma unroll
        for (int off = 32; off; off >>= 1) {
            s += __shfl_xor(s, off); qq2 += __shfl_xor(qq2, off);
        }
        if (l == 0) { sred[q][w4][0] = s; sred[q][w4][1] = qq2; }
    }
    __syncthreads();                                       // (3)
    {
        float ss  = sred[q][0][0] + sred[q][1][0] + sred[q][2][0] + sred[q][3][0];
        float qq2 = sred[q][0][1] + sred[q][1][1] + sred[q][2][1] + sred[q][3][1];
        float mu = ss * (1.0f / HID);
        float inv = rsqrtf(qq2 * (1.0f / HID) - mu * mu + 1e-5f);
        float nv = (v - mu) * inv * P.ln_g[col] + P.ln_b[col];
        nrm[q][col] = nv;
        P.N0[(size_t)(m0 + q) * HID + col] = nv;
    }
    __syncthreads();                                       // (4)

    // fused 3 projections to layer-1 inputs
    {
        const float* mW1a1 = P.msg_W1 + (size_t)1 * 2 * HID * HID;
        const float* uW1a1 = P.upd_W1 + (size_t)1 * 2 * HID * HID;
        float o3[3][4];
        rows4_q3(nrm, mW1a1, mW1a1 + (size_t)HID * HID, uW1a1, col, q, o3);
#pragma unroll
        for (int p = 0; p < 3; ++p)
#pragma unroll
            for (int ii = 0; ii < 4; ++ii) part3[p][q][ii][col] = o3[p][ii];
    }
    __syncthreads();                                       // (5)
    if (q < 3) {
        float* po = (q == 0) ? P.aB : (q == 1) ? P.bbB : P.p1B;
#pragma unroll
        for (int ii = 0; ii < 4; ++ii) {
            float s = part3[q][0][ii][col] + part3[q][1][ii][col]
                    + part3[q][2][ii][col] + part3[q][3][ii][col];
            po[(size_t)(m0 + ii) * HID + col] = s;
        }
    }
}

// ---------------------------------------------------------------------------
// Fused aggregate + u1 + resid + LN + fused next-layer projection.
// 1024 threads, grid 256. Barrier phases: 9; all-quarter reduces.
// ---------------------------------------------------------------------------
__global__ __launch_bounds__(1024) void aggproj_kernel(
    const float* __restrict__ a, const float* __restrict__ bbv,
    const float* __restrict__ mb1, const float* __restrict__ Aw,
    const float* __restrict__ rsumv,
    const float* __restrict__ P1, const float* __restrict__ W2u,
    const float* __restrict__ mb2u, const float* __restrict__ ub1,
    const float* __restrict__ uW2, const float* __restrict__ ub2,
    const float* __restrict__ Nprev, const float* __restrict__ lng,
    const float* __restrict__ lnb, float* __restrict__ Nout,
    const float* __restrict__ pw0, const float* __restrict__ pb0, float* __restrict__ o0,
    const float* __restrict__ pw1, const float* __restrict__ pb1, float* __restrict__ o1,
    const float* __restrict__ pw2, const float* __restrict__ pb2, float* __restrict__ o2,
    float* __restrict__ gzero)
{
    __shared__ float ap[4][HID];
    __shared__ float u1s[4][HID];
    __shared__ float nrm[4][HID];
    __shared__ float awr[4][NR];
    __shared__ float part3[3][4][4][HID];
    __shared__ float sred[4][4][2];
    int blk = blockIdx.x;
    int b  = blk >> 5;
    int i0 = (blk & 31) * 4;
    int m0 = b * NR + i0;
    int t  = threadIdx.x;
    int col = t & 255, q = t >> 8;
    int w4 = (t >> 6) & 3, l = t & 63;

    if (gzero && blk == 0 && q == 0) {
#pragma unroll
        for (int i = 0; i < 8; ++i) gzero[i * 256 + col] = 0.f;
    }

    // stage adjacency rows: threads 0..511 cover 4x128
    if (t < 512) awr[t >> 7][t & 127] = Aw[(i0 + (t >> 7)) * NR + (t & 127)];

    float bias = mb1[col];
    float ai[4];
#pragma unroll
    for (int ii = 0; ii < 4; ++ii)
        ai[ii] = a[(size_t)(m0 + ii) * HID + col] + bias;
    __syncthreads();                                       // (1)

    // aggregate partials, j-quarter: q sums j in [q*32, q*32+32)
    {
        float acc[4] = {0.f, 0.f, 0.f, 0.f};
        const float* bbb = &bbv[(size_t)b * NR * HID + col];
        int jb = q * 32;
#pragma unroll 4
        for (int j = 0; j < 32; ++j) {
            float bj = bbb[(size_t)(jb + j) * HID];
#pragma unroll
            for (int ii = 0; ii < 4; ++ii) {
                float pre = fmaxf(ai[ii] + bj, 0.0f);
                acc[ii] += awr[ii][jb + j] * pre;
            }
        }
#pragma unroll
        for (int ii = 0; ii < 4; ++ii) part3[0][q][ii][col] = acc[ii];
    }
    __syncthreads();                                       // (2)
    ap[q][col] = part3[0][0][q][col] + part3[0][1][q][col]
               + part3[0][2][q][col] + part3[0][3][q][col];
    __syncthreads();                                       // (3)

    // W2u pass -> u1
    {
        float o[4];
        rows4_q(ap, W2u, col, q, o);
#pragma unroll
        for (int ii = 0; ii < 4; ++ii) part3[0][q][ii][col] = o[ii];
    }
    __syncthreads();                                       // (4)
    {
        float w2f = part3[0][0][q][col] + part3[0][1][q][col]
                  + part3[0][2][q][col] + part3[0][3][q][col];
        float vv = w2f + P1[(size_t)(m0 + q) * HID + col]
                 + rsumv[i0 + q] * mb2u[col] + ub1[col];
        u1s[q][col] = fmaxf(vv, 0.0f);
    }
    __syncthreads();                                       // (5)

    // uW2 -> v, LN
    {
        float o[4];
        rows4_q(u1s, uW2, col, q, o);
#pragma unroll
        for (int ii = 0; ii < 4; ++ii) part3[0][q][ii][col] = o[ii];
    }
    __syncthreads();                                       // (6)
    float v;
    {
        float uf = part3[0][0][q][col] + part3[0][1][q][col]
                 + part3[0][2][q][col] + part3[0][3][q][col];
        v = Nprev[(size_t)(m0 + q) * HID + col] + uf + ub2[col];
        float s = v, qq2 = v * v;
#pragma unroll
        for (int off = 32; off; off >>= 1) {
            s += __shfl_xor(s, off); qq2 += __shfl_xor(qq2, off);
        }
        if (l == 0) { sred[q][w4][0] = s; sred[q][w4][1] = qq2; }
    }
    __syncthreads();                                       // (7)
    {
        float ss  = sred[q][0][0] + sred[q][1][0] + sred[q][2][0] + sred[q][3][0];
        float qq2 = sred[q][0][1] + sred[q][1][1] + sred[q][2][1] + sred[q][3][1];
        float mu = ss * (1.0f / HID);
        float inv = rsqrtf(qq2 * (1.0f / HID) - mu * mu + 1e-5f);
        float nv = (v - mu) * inv * lng[col] + lnb[col];
        nrm[q][col] = nv;
        Nout[(size_t)(m0 + q) * HID + col] = nv;
    }
    __syncthreads();                                       // (8)

    // fused 3 projections
    {
        float o3[3][4];
        rows4_q3(nrm, pw0, pw1, pw2, col, q, o3);
#pragma unroll
        for (int p = 0; p < 3; ++p)
#pragma unroll
            for (int ii = 0; ii < 4; ++ii) part3[p][q][ii][col] = o3[p][ii];
    }
    __syncthreads();                                       // (9)
    if (q < 3) {
        const float* pb = (q == 0) ? pb0 : (q == 1) ? pb1 : pb2;
        float* po = (q == 0) ? o0 : (q == 1) ? o1 : o2;
        float pbv = pb ? pb[col] : 0.f;
#pragma unroll
        for (int ii = 0; ii < 4; ++ii) {
            float s = part3[q][0][ii][col] + part3[q][1][ii][col]
                    + part3[q][2][ii][col] + part3[q][3][ii][col] + pbv;
            po[(size_t)(m0 + ii) * HID + col] = s;
        }
    }
}

// ---------------------------------------------------------------------------
// Fused attention + mean: 16 q-rows per block, one (b,head).
// XCD-locality swizzle: bh = blk & 31, ig = blk >> 5. Under round-robin
// block->XCD assignment, the 8 ig-blocks sharing one (b,head)'s 32KB K/V
// tiles are all blk === bh (mod 8) -> same XCD -> tiles fetched once per L2
// instead of 8x (round-9 counters: 9.4MB FETCH @ 237 GB/s = the kernel cost).
// ---------------------------------------------------------------------------
__global__ __launch_bounds__(256) void attention_kernel(
    const float* __restrict__ q, const float* __restrict__ k,
    const float* __restrict__ v, float* __restrict__ gacc)
{
    __shared__ struct { float KhT[64][128]; float S[16][128]; float qs[16][64]; } L;
    int blk = blockIdx.x;
    int bh = blk & 31, ig = blk >> 5;     // swizzled (was bh = blk>>3, ig = blk&7)
    int b = bh >> 2, hd = bh & 3;
    int i0 = ig * 16;
    int t = threadIdx.x;
    const float* qg = q + ((size_t)b * NR) * HID + hd * DHD;
    const float* kg = k + ((size_t)b * NR) * HID + hd * DHD;
    const float* vg = v + ((size_t)b * NR) * HID + hd * DHD;

    {   // stage K^T
        int j = t >> 1, half = t & 1;
        const float* krow = kg + (size_t)j * HID + half * 32;
#pragma unroll
        for (int c = 0; c < 32; c += 4) {
            float4 kv = *(const float4*)(krow + c);
            L.KhT[half * 32 + c + 0][j] = kv.x;
            L.KhT[half * 32 + c + 1][j] = kv.y;
            L.KhT[half * 32 + c + 2][j] = kv.z;
            L.KhT[half * 32 + c + 3][j] = kv.w;
        }
    }
    {   // stage q rows
        int ii = t >> 4, d0 = (t & 15) * 4;
        *(float4*)&L.qs[ii][d0] = *(const float4*)(qg + (size_t)(i0 + ii) * HID + d0);
    }
    __syncthreads();
    {   // scores
        int j = t & 127, ii2 = t >> 7;
        float acc[8] = {0.f,0.f,0.f,0.f,0.f,0.f,0.f,0.f};
#pragma unroll 4
        for (int d = 0; d < 64; ++d) {
            float kv = L.KhT[d][j];
#pragma unroll
            for (int ii = 0; ii < 8; ++ii) acc[ii] += L.qs[ii2 * 8 + ii][d] * kv;
        }
#pragma unroll
        for (int ii = 0; ii < 8; ++ii) L.S[ii2 * 8 + ii][j] = acc[ii] * 0.125f;
    }
    __syncthreads();
    {   // softmax per row
        int w = t >> 6, l = t & 63;
#pragma unroll
        for (int r = w * 4; r < w * 4 + 4; ++r) {
            float e0 = L.S[r][l], e1 = L.S[r][l + 64];
            float mx = fmaxf(e0, e1);
#pragma unroll
            for (int off = 32; off; off >>= 1) mx = fmaxf(mx, __shfl_xor(mx, off));
            e0 = expf(e0 - mx); e1 = expf(e1 - mx);
            float sm = e0 + e1;
#pragma unroll
            for (int off = 32; off; off >>= 1) sm += __shfl_xor(sm, off);
            float inv = 1.0f / sm;
            L.S[r][l] = e0 * inv; L.S[r][l + 64] = e1 * inv;
        }
    }
    __syncthreads();
    {   // PV + row-sum into gacc
        int d = t & 63, ir = t >> 6;
        float accv[4] = {0.f, 0.f, 0.f, 0.f};
        const float* vp = vg + d;
#pragma unroll 8
        for (int j = 0; j < NR; ++j) {
            float vv = vp[(size_t)j * HID];
#pragma unroll
            for (int p = 0; p < 4; ++p) accv[p] += L.S[p * 4 + ir][j] * vv;
        }
        float s = accv[0] + accv[1] + accv[2] + accv[3];
        atomicAdd(&gacc[b * HID + hd * DHD + d], s);
    }
}

// ---------------------------------------------------------------------------
// Fused tail: per-batch chain. 8 blocks.
// ---------------------------------------------------------------------------
__global__ __launch_bounds__(256) void tailf_kernel(KP P) {
    __shared__ float v0[HID], v1[HID], v2[HID];
    __shared__ float red[1024];
    int b = blockIdx.x;
    int t = threadIdx.x;
    int w = t >> 6, l = t & 63;

    v0[t] = P.gacc[b * HID + t] * (1.0f / NR);
    __syncthreads();
    gemv256w(v0, P.Wo, P.bo, 0, v1, red);
    gemv256w(v1, P.ro_W1, P.ro_b1, 1, v2, red);

    {   // logits: N=128; lane l -> outputs 2l,2l+1; wave w -> K quarter
        float2 acc = {0.f, 0.f};
        const float* Wp = P.ro_W2 + (size_t)(w * 64) * NR + l * 2;
        const float* xp = v2 + w * 64;
#pragma unroll 8
        for (int kk = 0; kk < 64; ++kk) {
            float xv = xp[kk];
            float2 wv = *(const float2*)(Wp + (size_t)kk * NR);
            acc.x += xv * wv.x; acc.y += xv * wv.y;
        }
        *(float2*)&red[w * 128 + l * 2] = acc;
        __syncthreads();
    }
    float logit = -1e30f;
    if (t < NR) logit = red[t] + red[128 + t] + red[256 + t] + red[384 + t] + P.ro_b2[t];
    __syncthreads();
    float m = logit;
#pragma unroll
    for (int off = 32; off; off >>= 1) m = fmaxf(m, __shfl_xor(m, off));
    if (l == 0) red[w] = m;
    __syncthreads();
    m = fmaxf(red[0], red[1]);
    float e = (t < NR) ? expf(logit - m) : 0.0f;
    float ssum = e;
#pragma unroll
    for (int off = 32; off; off >>= 1) ssum += __shfl_xor(ssum, off);
    if (l == 0) red[4 + w] = ssum;
    __syncthreads();
    float tot = red[4] + red[5];
    if (t < NR) P.out[b * NR + t] = e / tot;
}

// ---------------------------------------------------------------------------
extern "C" void kernel_launch(void* const* d_in, const int* in_sizes, int n_in,
                              void* d_out, int out_size, void* d_ws, size_t ws_size,
                              hipStream_t stream)
{
    KP P;
    P.x        = (const float*)d_in[0];
    P.We       = (const float*)d_in[1];
    P.be       = (const float*)d_in[2];
    P.msg_W1   = (const float*)d_in[3];
    P.msg_b1   = (const float*)d_in[4];
    P.msg_W2   = (const float*)d_in[5];
    P.msg_b2   = (const float*)d_in[6];
    P.upd_W1   = (const float*)d_in[7];
    P.upd_b1   = (const float*)d_in[8];
    P.upd_W2   = (const float*)d_in[9];
    P.upd_b2   = (const float*)d_in[10];
    P.ln_g     = (const float*)d_in[11];
    P.ln_b     = (const float*)d_in[12];
    P.rule_adj = (const float*)d_in[13];
    P.Wq       = (const float*)d_in[14];
    P.bq       = (const float*)d_in[15];
    P.Wk       = (const float*)d_in[16];
    P.bk       = (const float*)d_in[17];
    P.Wv       = (const float*)d_in[18];
    P.bv       = (const float*)d_in[19];
    P.Wo       = (const float*)d_in[20];
    P.bo       = (const float*)d_in[21];
    P.ro_W1    = (const float*)d_in[22];
    P.ro_b1    = (const float*)d_in[23];
    P.ro_W2    = (const float*)d_in[24];
    P.ro_b2    = (const float*)d_in[25];
    P.out      = (float*)d_out;

    float* b0 = (float*)d_ws;
    P.N0     = b0;  b0 += SZ;
    P.N1     = b0;  b0 += SZ;
    P.N2     = b0;  b0 += SZ;
    P.aB     = b0;  b0 += SZ;
    P.bbB    = b0;  b0 += SZ;
    P.p1B    = b0;  b0 += SZ;
    P.aA     = b0;  b0 += SZ;
    P.bbA    = b0;  b0 += SZ;
    P.p1A    = b0;  b0 += SZ;
    P.W2u    = b0;  b0 += 3 * HID * HID;
    P.mb2u   = b0;  b0 += 3 * HID;
    P.mW1s   = b0;  b0 += HID * HID;
    P.Aw     = b0;  b0 += NR * NR;
    P.rsum   = b0;  b0 += NR;
    P.h0g    = b0;  b0 += NB * HID;
    P.c0g    = b0;  b0 += NB * HID;
    P.c1g    = b0;  b0 += NB * HID;
    P.gacc   = b0;  b0 += NB * HID;
    P.scratch= b0;  b0 += 256;

    // 1. setup: adj | W2u (3 layers) | mb2u | h0 | mW1s | prefetch
    setup0_kernel<<<dim3(256), 256, 0, stream>>>(P);

    // 1b. per-batch layer-0 head chain (c0, c1)
    setup1_kernel<<<dim3(8), 256, 0, stream>>>(P);

    // 2. layer 0 (head chain hoisted) + projection to layer-1 inputs (set B)
    layer0p_kernel<<<dim3(256), 1024, 0, stream>>>(P);

    // 3. layer 1: agg + resid + LN + projection to layer-2 inputs (set A)
    {
        const int l = 1;
        const float* mW1a2 = P.msg_W1 + (size_t)2 * 2 * HID * HID;
        const float* uW1a2 = P.upd_W1 + (size_t)2 * 2 * HID * HID;
        aggproj_kernel<<<dim3(256), 1024, 0, stream>>>(
            P.aB, P.bbB, P.msg_b1 + (size_t)l * HID, P.Aw, P.rsum,
            P.p1B, P.W2u + (size_t)l * HID * HID, P.mb2u + l * HID,
            P.upd_b1 + (size_t)l * HID,
            P.upd_W2 + (size_t)l * HID * HID, P.upd_b2 + (size_t)l * HID,
            P.N0, P.ln_g + (size_t)l * HID, P.ln_b + (size_t)l * HID, P.N1,
            mW1a2, nullptr, P.aA,
            mW1a2 + (size_t)HID * HID, nullptr, P.bbA,
            uW1a2, nullptr, P.p1A,
            nullptr);
    }

    // 4. layer 2: agg + resid + LN + projection to q/k/v (set B); zeroes gacc
    {
        const int l = 2;
        aggproj_kernel<<<dim3(256), 1024, 0, stream>>>(
            P.aA, P.bbA, P.msg_b1 + (size_t)l * HID, P.Aw, P.rsum,
            P.p1A, P.W2u + (size_t)l * HID * HID, P.mb2u + l * HID,
            P.upd_b1 + (size_t)l * HID,
            P.upd_W2 + (size_t)l * HID * HID, P.upd_b2 + (size_t)l * HID,
            P.N1, P.ln_g + (size_t)l * HID, P.ln_b + (size_t)l * HID, P.N2,
            P.Wq, P.bq, P.aB,
            P.Wk, P.bk, P.bbB,
            P.Wv, P.bv, P.p1B,
            P.gacc);
    }

    // 5. attention + mean (atomic into gacc)
    attention_kernel<<<dim3(256), 256, 0, stream>>>(P.aB, P.bbB, P.p1B, P.gacc);

    // 6. fused tail
    tailf_kernel<<<dim3(8), 256, 0, stream>>>(P);
}